// Round 1
// baseline (356.370 us; speedup 1.0000x reference)
//
#include <hip/hip_runtime.h>

#define NTOK 262144   // 64*64*64 tokens per batch
#define NCH  64
#define NB   4
#define T    128      // tokens per tile
#define XSS  129      // xs stride (odd -> conflict-free transpose reads)

// ws layout (floats): S[4][4] @0, m[4][4][64] @16, rc[4][64] @1040
#define WS_S  0
#define WS_M  16
#define WS_RC 1040

__global__ __launch_bounds__(256, 4)
void ea3d_reduce(const float* __restrict__ x, const float* __restrict__ Wk,
                 float* __restrict__ ws)
{
    __shared__ float xs[NCH * XSS];              // transposed tile [c][t]
    __shared__ __align__(16) float es[T * 4];    // e[t][h]
    __shared__ __align__(16) float wk4[NCH * 4]; // Wk transposed: wk4[c][h]

    const int tid = threadIdx.x;
    const int w   = tid >> 6;        // wave 0..3 -> token quarter
    const int l   = tid & 63;        // lane
    const int b   = blockIdx.y;

    {   // stage Wk transposed (once)
        int c = tid >> 2, h = tid & 3;
        wk4[(c << 2) + h] = Wk[h * NCH + c];
    }
    __syncthreads();

    const int tA  = (w << 5) + (l & 31);   // this lane's token within tile
    const int chA = (l >> 5) << 5;         // channel half: 0 or 32
    const float* xb = x + (size_t)b * NCH * NTOK;

    float macc0 = 0.f, macc1 = 0.f, macc2 = 0.f, macc3 = 0.f; // m[h][c=l] partials
    float sacc0 = 0.f, sacc1 = 0.f, sacc2 = 0.f, sacc3 = 0.f; // S[h] partials (l<32)

    for (int n0 = blockIdx.x * T; n0 < NTOK; n0 += gridDim.x * T) {
        // ---- phase A: load quarter (all 64 ch for 32 tokens), stage + keys ----
        float k0 = 0.f, k1 = 0.f, k2 = 0.f, k3 = 0.f;
        const float* xp = xb + (size_t)chA * NTOK + n0 + tA;
        float* xsw = xs + (chA * XSS) + tA;
        const float4* wkp = (const float4*)(wk4) + chA;
        #pragma unroll 8
        for (int ci = 0; ci < 32; ++ci) {
            float xv = xp[(size_t)ci * NTOK];
            float4 wv = wkp[ci];
            xsw[ci * XSS] = xv;
            k0 += wv.x * xv; k1 += wv.y * xv; k2 += wv.z * xv; k3 += wv.w * xv;
        }
        // combine channel halves (lane l <-> l^32)
        k0 += __shfl_xor(k0, 32);
        k1 += __shfl_xor(k1, 32);
        k2 += __shfl_xor(k2, 32);
        k3 += __shfl_xor(k3, 32);
        if (l < 32) {
            float e0 = __expf(k0), e1 = __expf(k1), e2 = __expf(k2), e3 = __expf(k3);
            *((float4*)es + tA) = make_float4(e0, e1, e2, e3);
            sacc0 += e0; sacc1 += e1; sacc2 += e2; sacc3 += e3;
        }
        // ---- phase B: lane = channel, sweep this wave's 32 tokens ----
        // (same wave produced this quarter's xs/es -> no __syncthreads needed)
        const float*  xrow = xs + l * XSS + (w << 5);
        const float4* erow = (const float4*)es + (w << 5);
        #pragma unroll 8
        for (int i = 0; i < 32; ++i) {
            float  xv = xrow[i];
            float4 e4 = erow[i];
            macc0 += e4.x * xv; macc1 += e4.y * xv;
            macc2 += e4.z * xv; macc3 += e4.w * xv;
        }
    }

    // m[b][h][c=l] partial per wave -> global accumulate
    float* mb = ws + WS_M + (size_t)(b * 4) * NCH + l;
    __hip_atomic_fetch_add(mb + 0 * NCH, macc0, __ATOMIC_RELAXED, __HIP_MEMORY_SCOPE_AGENT);
    __hip_atomic_fetch_add(mb + 1 * NCH, macc1, __ATOMIC_RELAXED, __HIP_MEMORY_SCOPE_AGENT);
    __hip_atomic_fetch_add(mb + 2 * NCH, macc2, __ATOMIC_RELAXED, __HIP_MEMORY_SCOPE_AGENT);
    __hip_atomic_fetch_add(mb + 3 * NCH, macc3, __ATOMIC_RELAXED, __HIP_MEMORY_SCOPE_AGENT);

    // S: reduce over lanes 0..31 of this wave
    for (int off = 16; off; off >>= 1) {
        sacc0 += __shfl_down(sacc0, off, 32);
        sacc1 += __shfl_down(sacc1, off, 32);
        sacc2 += __shfl_down(sacc2, off, 32);
        sacc3 += __shfl_down(sacc3, off, 32);
    }
    if (l == 0) {
        float* sb = ws + WS_S + b * 4;
        __hip_atomic_fetch_add(sb + 0, sacc0, __ATOMIC_RELAXED, __HIP_MEMORY_SCOPE_AGENT);
        __hip_atomic_fetch_add(sb + 1, sacc1, __ATOMIC_RELAXED, __HIP_MEMORY_SCOPE_AGENT);
        __hip_atomic_fetch_add(sb + 2, sacc2, __ATOMIC_RELAXED, __HIP_MEMORY_SCOPE_AGENT);
        __hip_atomic_fetch_add(sb + 3, sacc3, __ATOMIC_RELAXED, __HIP_MEMORY_SCOPE_AGENT);
    }
}

__global__ void ea3d_finalize(const float* __restrict__ Wv, const float* __restrict__ bv,
                              const float* __restrict__ Wr, const float* __restrict__ br,
                              float* __restrict__ ws)
{
    __shared__ float ctx[NB * 32];
    const int tid = threadIdx.x;
    if (tid < 128) {
        int b = tid >> 5, hv = tid & 31, h = hv >> 3;
        float inv = 1.0f / ws[WS_S + b * 4 + h];
        const float* m = ws + WS_M + (b * 4 + h) * NCH;
        const float* wvr = Wv + hv * NCH;
        float acc = 0.f;
        #pragma unroll
        for (int c = 0; c < NCH; ++c) acc += wvr[c] * m[c];
        ctx[b * 32 + hv] = acc * inv + bv[hv];
    }
    __syncthreads();
    int b = tid >> 6, c = tid & 63;
    const float* wrr = Wr + c * 32;
    const float* cb  = ctx + b * 32;
    float acc = br[c];
    #pragma unroll
    for (int hv = 0; hv < 32; ++hv) acc += wrr[hv] * cb[hv];
    ws[WS_RC + b * NCH + c] = acc;
}

__global__ __launch_bounds__(256)
void ea3d_add(const float* __restrict__ x, const float* __restrict__ ws,
              float* __restrict__ out)
{
    const int row = blockIdx.y;                 // b*64 + c
    const float rc = ws[WS_RC + row];
    const size_t base = (size_t)row * NTOK;
    const float4* xp = (const float4*)(x + base);
    float4*       op = (float4*)(out + base);
    const int nvec = NTOK / 4;
    for (int i = blockIdx.x * blockDim.x + threadIdx.x; i < nvec;
         i += gridDim.x * blockDim.x) {
        float4 v = xp[i];
        v.x += rc; v.y += rc; v.z += rc; v.w += rc;
        op[i] = v;
    }
}

extern "C" void kernel_launch(void* const* d_in, const int* in_sizes, int n_in,
                              void* d_out, int out_size, void* d_ws, size_t ws_size,
                              hipStream_t stream)
{
    const float* x  = (const float*)d_in[0];
    const float* Wk = (const float*)d_in[1];
    // d_in[2]=bk (cancels in softmax), d_in[3]=Wq, d_in[4]=bq (softmax over size-1 axis -> 1.0)
    const float* Wv = (const float*)d_in[5];
    const float* bv = (const float*)d_in[6];
    const float* Wr = (const float*)d_in[7];
    const float* br = (const float*)d_in[8];
    float* out = (float*)d_out;
    float* ws  = (float*)d_ws;

    hipMemsetAsync(ws, 0, (WS_RC) * sizeof(float), stream);  // zero S + m accumulators
    ea3d_reduce<<<dim3(256, NB), 256, 0, stream>>>(x, Wk, ws);
    ea3d_finalize<<<1, 256, 0, stream>>>(Wv, bv, Wr, br, ws);
    ea3d_add<<<dim3(32, NB * NCH), 256, 0, stream>>>(x, ws, out);
}

// Round 2
// 349.423 us; speedup vs baseline: 1.0199x; 1.0199x over previous
//
#include <hip/hip_runtime.h>

#define NTOK 262144   // 64*64*64 tokens per batch
#define NCH  64
#define NB   4

#define BTOK 128      // tokens per block-tile (4 waves x 32)
#define WTOK 32       // tokens per wave-tile
#define XSS  33       // per-channel LDS stride (floats) -> conflict-free transpose
#define GRIDX 256
#define NIT  (NTOK / (GRIDX * BTOK))   // 8 iterations

// ws layout (floats): S[4][4] @0, m[4][4][64] @16, rc[4][64] @1040
#define WS_S  0
#define WS_M  16
#define WS_RC 1040

__global__ __launch_bounds__(256, 4)
void ea3d_reduce(const float* __restrict__ x, const float* __restrict__ Wk,
                 float* __restrict__ ws)
{
    __shared__ float xs[4][NCH * XSS];          // per-wave transposed tile [c][t]
    __shared__ __align__(16) float es[4][WTOK * 4];   // per-wave e[t][h]
    __shared__ __align__(16) float wk4[NCH * 4];      // Wk transposed: wk4[c][h]

    const int tid = threadIdx.x;
    const int w   = tid >> 6;        // wave id 0..3
    const int l   = tid & 63;        // lane
    const int b   = blockIdx.y;

    {   // stage Wk transposed (once)
        int c = tid >> 2, h = tid & 3;
        wk4[(c << 2) + h] = Wk[h * NCH + c];
    }
    __syncthreads();

    const int cg = l >> 3;           // channel sub-group: lane covers channels 8i+cg
    const int tq = (l & 7) << 2;     // token offset (float4) within wave-tile
    const float* xb = x + (size_t)b * NCH * NTOK + (size_t)cg * NTOK;
    float* xsw = xs[w];
    float* esw = es[w];

    float macc[4] = {0.f, 0.f, 0.f, 0.f};   // m[h][c=l] partials
    float sacc[4] = {0.f, 0.f, 0.f, 0.f};   // S[h] partials (x8 redundant)

    const size_t base0 = (size_t)blockIdx.x * BTOK + (w << 5) + tq;
    const size_t step  = (size_t)GRIDX * BTOK;

    // prologue: issue tile-0 loads (8 independent dwordx4)
    float4 xv[8];
    {
        const float* xp = xb + base0;
        #pragma unroll
        for (int i = 0; i < 8; ++i)
            xv[i] = *(const float4*)(xp + (size_t)(i << 3) * NTOK);
    }

    for (int it = 0; it < NIT; ++it) {
        // ---- consume registers: keys FMA + transposed LDS stage ----
        float kk[16];   // kk[j*4+h]
        #pragma unroll
        for (int r = 0; r < 16; ++r) kk[r] = 0.f;
        #pragma unroll
        for (int i = 0; i < 8; ++i) {
            const int c = (i << 3) + cg;
            float4 wv = *((const float4*)wk4 + c);
            float* xd = xsw + c * XSS + tq;
            xd[0] = xv[i].x; xd[1] = xv[i].y; xd[2] = xv[i].z; xd[3] = xv[i].w;
            kk[0]  += wv.x * xv[i].x; kk[1]  += wv.y * xv[i].x;
            kk[2]  += wv.z * xv[i].x; kk[3]  += wv.w * xv[i].x;
            kk[4]  += wv.x * xv[i].y; kk[5]  += wv.y * xv[i].y;
            kk[6]  += wv.z * xv[i].y; kk[7]  += wv.w * xv[i].y;
            kk[8]  += wv.x * xv[i].z; kk[9]  += wv.y * xv[i].z;
            kk[10] += wv.z * xv[i].z; kk[11] += wv.w * xv[i].z;
            kk[12] += wv.x * xv[i].w; kk[13] += wv.y * xv[i].w;
            kk[14] += wv.z * xv[i].w; kk[15] += wv.w * xv[i].w;
        }

        // ---- issue NEXT tile's loads now (overlap with shuffles/exp/phase B) ----
        if (it + 1 < NIT) {
            const float* xp = xb + base0 + (size_t)(it + 1) * step;
            #pragma unroll
            for (int i = 0; i < 8; ++i)
                xv[i] = *(const float4*)(xp + (size_t)(i << 3) * NTOK);
        }

        // ---- reduce keys across the 8 channel groups ----
        #pragma unroll
        for (int m = 8; m <= 32; m <<= 1) {
            #pragma unroll
            for (int r = 0; r < 16; ++r) kk[r] += __shfl_xor(kk[r], m);
        }

        // ---- exp, stage e[t][h], accumulate S (x8 redundant, scaled later) ----
        float e[16];
        #pragma unroll
        for (int r = 0; r < 16; ++r) e[r] = __expf(kk[r]);
        if (cg == 0) {
            #pragma unroll
            for (int j = 0; j < 4; ++j)
                *((float4*)esw + (tq + j)) =
                    make_float4(e[j*4+0], e[j*4+1], e[j*4+2], e[j*4+3]);
        }
        #pragma unroll
        for (int h = 0; h < 4; ++h)
            sacc[h] += e[0*4+h] + e[1*4+h] + e[2*4+h] + e[3*4+h];

        // ---- phase B: lane = channel, sweep the wave's 32 tokens ----
        const float* xrow = xsw + l * XSS;
        const float4* erow = (const float4*)esw;
        #pragma unroll 8
        for (int t = 0; t < WTOK; ++t) {
            float  xvv = xrow[t];
            float4 e4  = erow[t];
            macc[0] += e4.x * xvv; macc[1] += e4.y * xvv;
            macc[2] += e4.z * xvv; macc[3] += e4.w * xvv;
        }
    }

    // m[b][h][c=l] partial per wave -> global accumulate
    float* mb = ws + WS_M + (size_t)(b * 4) * NCH + l;
    #pragma unroll
    for (int h = 0; h < 4; ++h)
        __hip_atomic_fetch_add(mb + h * NCH, macc[h],
                               __ATOMIC_RELAXED, __HIP_MEMORY_SCOPE_AGENT);

    // S: reduce over all 64 lanes (each token counted 8x -> scale 0.125)
    #pragma unroll
    for (int h = 0; h < 4; ++h) {
        float v = sacc[h];
        #pragma unroll
        for (int off = 32; off; off >>= 1) v += __shfl_xor(v, off);
        sacc[h] = v;
    }
    if (l == 0) {
        float* sb = ws + WS_S + b * 4;
        #pragma unroll
        for (int h = 0; h < 4; ++h)
            __hip_atomic_fetch_add(sb + h, 0.125f * sacc[h],
                                   __ATOMIC_RELAXED, __HIP_MEMORY_SCOPE_AGENT);
    }
}

__global__ void ea3d_finalize(const float* __restrict__ Wv, const float* __restrict__ bv,
                              const float* __restrict__ Wr, const float* __restrict__ br,
                              float* __restrict__ ws)
{
    __shared__ float ctx[NB * 32];
    const int tid = threadIdx.x;
    if (tid < 128) {
        int b = tid >> 5, hv = tid & 31, h = hv >> 3;
        float inv = 1.0f / ws[WS_S + b * 4 + h];
        const float* m = ws + WS_M + (b * 4 + h) * NCH;
        const float* wvr = Wv + hv * NCH;
        float acc = 0.f;
        #pragma unroll
        for (int c = 0; c < NCH; ++c) acc += wvr[c] * m[c];
        ctx[b * 32 + hv] = acc * inv + bv[hv];
    }
    __syncthreads();
    int b = tid >> 6, c = tid & 63;
    const float* wrr = Wr + c * 32;
    const float* cb  = ctx + b * 32;
    float acc = br[c];
    #pragma unroll
    for (int hv = 0; hv < 32; ++hv) acc += wrr[hv] * cb[hv];
    ws[WS_RC + b * NCH + c] = acc;
}

__global__ __launch_bounds__(256)
void ea3d_add(const float* __restrict__ x, const float* __restrict__ ws,
              float* __restrict__ out)
{
    const int row = blockIdx.y;                 // b*64 + c
    const float rc = ws[WS_RC + row];
    const size_t base = (size_t)row * NTOK;
    const float4* xp = (const float4*)(x + base);
    float4*       op = (float4*)(out + base);
    const int nvec = NTOK / 4;
    for (int i = blockIdx.x * blockDim.x + threadIdx.x; i < nvec;
         i += gridDim.x * blockDim.x) {
        float4 v = xp[i];
        v.x += rc; v.y += rc; v.z += rc; v.w += rc;
        op[i] = v;
    }
}

extern "C" void kernel_launch(void* const* d_in, const int* in_sizes, int n_in,
                              void* d_out, int out_size, void* d_ws, size_t ws_size,
                              hipStream_t stream)
{
    const float* x  = (const float*)d_in[0];
    const float* Wk = (const float*)d_in[1];
    // d_in[2]=bk (cancels in token-softmax); d_in[3]=Wq, d_in[4]=bq (softmax over
    // size-1 head-channel axis -> identically 1.0, so Wq/bq are dead)
    const float* Wv = (const float*)d_in[5];
    const float* bv = (const float*)d_in[6];
    const float* Wr = (const float*)d_in[7];
    const float* br = (const float*)d_in[8];
    float* out = (float*)d_out;
    float* ws  = (float*)d_ws;

    hipMemsetAsync(ws, 0, (WS_RC) * sizeof(float), stream);  // zero S + m accumulators
    ea3d_reduce<<<dim3(GRIDX, NB), 256, 0, stream>>>(x, Wk, ws);
    ea3d_finalize<<<1, 256, 0, stream>>>(Wv, bv, Wr, br, ws);
    ea3d_add<<<dim3(32, NB * NCH), 256, 0, stream>>>(x, ws, out);
}

// Round 3
// 247.218 us; speedup vs baseline: 1.4415x; 1.4134x over previous
//
#include <hip/hip_runtime.h>

#define NTOK 262144   // 64*64*64 tokens per batch
#define NCH  64
#define NB   4

#define T     128     // tokens per block-tile
#define XSS   129     // xs row stride (floats) -> transpose reads are 2-way max (free)
#define GRIDX 128
#define NIT   (NTOK / (GRIDX * T))   // 16

// ws layout (floats): S[4][4] @0, m[4][4][64] @16, rc[4][64] @1040
#define WS_S  0
#define WS_M  16
#define WS_RC 1040

__global__ __launch_bounds__(256, 2)
void ea3d_reduce(const float* __restrict__ x, const float* __restrict__ Wk,
                 float* __restrict__ ws)
{
    __shared__ float xs[NCH * XSS];                   // tile [c][t], padded
    __shared__ __align__(16) float kpart[4 * 64 * 8]; // [w][lane][2tok x 4head]
    __shared__ __align__(16) float es[T * 4];         // e[t][h]
    __shared__ __align__(16) float wk4[NCH * 4];      // Wk transposed

    const int tid = threadIdx.x;
    const int w   = tid >> 6;        // wave 0..3 -> owns channels [16w,16w+16)
    const int l   = tid & 63;
    const int b   = blockIdx.y;

    { int c = tid >> 2, h = tid & 3; wk4[(c << 2) + h] = Wk[h * NCH + c]; }
    __syncthreads();

    const int c0 = w << 4;
    const float* xb = x + (size_t)b * NCH * NTOK + (size_t)c0 * NTOK;

    float macc[4] = {0.f, 0.f, 0.f, 0.f};
    float sacc[4] = {0.f, 0.f, 0.f, 0.f};

    const size_t tok0 = (size_t)blockIdx.x * T + (l << 1);  // lane's 2 tokens
    const size_t step = (size_t)GRIDX * T;

    // prologue: tile 0 — each wave loads its 16 channel-rows, 512B contiguous each
    float2 xv[16];
    {
        const float* xp = xb + tok0;
        #pragma unroll
        for (int i = 0; i < 16; ++i)
            xv[i] = *(const float2*)(xp + (size_t)i * NTOK);
    }

    for (int it = 0; it < NIT; ++it) {
        // ---- keys partial (this wave's 16 channels, lane's 2 tokens) ----
        float kk[8] = {0,0,0,0,0,0,0,0};
        #pragma unroll
        for (int i = 0; i < 16; ++i) {
            float4 wv = *((const float4*)wk4 + (c0 + i));
            kk[0] += wv.x * xv[i].x; kk[1] += wv.y * xv[i].x;
            kk[2] += wv.z * xv[i].x; kk[3] += wv.w * xv[i].x;
            kk[4] += wv.x * xv[i].y; kk[5] += wv.y * xv[i].y;
            kk[6] += wv.z * xv[i].y; kk[7] += wv.w * xv[i].y;
        }
        // ---- stage tile rows to LDS ----
        #pragma unroll
        for (int i = 0; i < 16; ++i)
            *(float2*)(xs + (c0 + i) * XSS + (l << 1)) = xv[i];
        // ---- cross-wave key partials ----
        *((float4*)kpart + ((w << 6) + l) * 2 + 0) = make_float4(kk[0], kk[1], kk[2], kk[3]);
        *((float4*)kpart + ((w << 6) + l) * 2 + 1) = make_float4(kk[4], kk[5], kk[6], kk[7]);

        // ---- prefetch next tile; stays in flight across raw barriers ----
        if (it + 1 < NIT) {
            const float* xp = xb + tok0 + (size_t)(it + 1) * step;
            #pragma unroll
            for (int i = 0; i < 16; ++i)
                xv[i] = *(const float2*)(xp + (size_t)i * NTOK);
        }

        asm volatile("s_waitcnt lgkmcnt(0)" ::: "memory");
        __builtin_amdgcn_s_barrier();          // raw barrier: vmcnt NOT drained
        asm volatile("" ::: "memory");

        // ---- sum partials, exp: token t = 32w + (l&31) (dup for l>=32) ----
        const int t = (w << 5) + (l & 31);
        float4 p0 = *((const float4*)kpart + (0 << 7) + t);   // byte: w'*2048 + t*16
        float4 p1 = *((const float4*)kpart + (1 << 7) + t);
        float4 p2 = *((const float4*)kpart + (2 << 7) + t);
        float4 p3 = *((const float4*)kpart + (3 << 7) + t);
        float e0 = __expf(p0.x + p1.x + p2.x + p3.x);
        float e1 = __expf(p0.y + p1.y + p2.y + p3.y);
        float e2 = __expf(p0.z + p1.z + p2.z + p3.z);
        float e3 = __expf(p0.w + p1.w + p2.w + p3.w);
        if (l < 32) *((float4*)es + t) = make_float4(e0, e1, e2, e3);
        sacc[0] += e0; sacc[1] += e1; sacc[2] += e2; sacc[3] += e3;  // x2 dup, scale later

        // ---- phase B: lane = channel, sweep this wave's 32 tokens ----
        const float*  xrow = xs + l * XSS + (w << 5);
        const float4* erow = (const float4*)es + (w << 5);
        #pragma unroll 8
        for (int tt = 0; tt < 32; ++tt) {
            float  xvv = xrow[tt];
            float4 e4  = erow[tt];
            macc[0] += e4.x * xvv; macc[1] += e4.y * xvv;
            macc[2] += e4.z * xvv; macc[3] += e4.w * xvv;
        }

        asm volatile("s_waitcnt lgkmcnt(0)" ::: "memory");
        __builtin_amdgcn_s_barrier();          // protect xs/kpart before next overwrite
        asm volatile("" ::: "memory");
    }

    // m[b][h][c=l] partial per wave -> global accumulate
    float* mb = ws + WS_M + (size_t)(b * 4) * NCH + l;
    #pragma unroll
    for (int h = 0; h < 4; ++h)
        __hip_atomic_fetch_add(mb + h * NCH, macc[h],
                               __ATOMIC_RELAXED, __HIP_MEMORY_SCOPE_AGENT);

    // S: reduce over 64 lanes (each token counted twice -> scale 0.5)
    #pragma unroll
    for (int h = 0; h < 4; ++h) {
        float v = sacc[h];
        #pragma unroll
        for (int off = 32; off; off >>= 1) v += __shfl_xor(v, off);
        sacc[h] = v;
    }
    if (l == 0) {
        float* sb = ws + WS_S + b * 4;
        #pragma unroll
        for (int h = 0; h < 4; ++h)
            __hip_atomic_fetch_add(sb + h, 0.5f * sacc[h],
                                   __ATOMIC_RELAXED, __HIP_MEMORY_SCOPE_AGENT);
    }
}

__global__ void ea3d_finalize(const float* __restrict__ Wv, const float* __restrict__ bv,
                              const float* __restrict__ Wr, const float* __restrict__ br,
                              float* __restrict__ ws)
{
    __shared__ float ctx[NB * 32];
    const int tid = threadIdx.x;
    if (tid < 128) {
        int b = tid >> 5, hv = tid & 31, h = hv >> 3;
        float inv = 1.0f / ws[WS_S + b * 4 + h];
        const float* m = ws + WS_M + (b * 4 + h) * NCH;
        const float* wvr = Wv + hv * NCH;
        float acc = 0.f;
        #pragma unroll
        for (int c = 0; c < NCH; ++c) acc += wvr[c] * m[c];
        ctx[b * 32 + hv] = acc * inv + bv[hv];
    }
    __syncthreads();
    int b = tid >> 6, c = tid & 63;
    const float* wrr = Wr + c * 32;
    const float* cb  = ctx + b * 32;
    float acc = br[c];
    #pragma unroll
    for (int hv = 0; hv < 32; ++hv) acc += wrr[hv] * cb[hv];
    ws[WS_RC + b * NCH + c] = acc;
}

__global__ __launch_bounds__(256)
void ea3d_add(const float* __restrict__ x, const float* __restrict__ ws,
              float* __restrict__ out)
{
    const int row = blockIdx.y;                 // b*64 + c
    const float rc = ws[WS_RC + row];
    const size_t base = (size_t)row * NTOK;
    const float4* xp = (const float4*)(x + base);
    float4*       op = (float4*)(out + base);
    const int nvec = NTOK / 4;
    for (int i = blockIdx.x * blockDim.x + threadIdx.x; i < nvec;
         i += gridDim.x * blockDim.x) {
        float4 v = xp[i];
        v.x += rc; v.y += rc; v.z += rc; v.w += rc;
        op[i] = v;
    }
}

extern "C" void kernel_launch(void* const* d_in, const int* in_sizes, int n_in,
                              void* d_out, int out_size, void* d_ws, size_t ws_size,
                              hipStream_t stream)
{
    const float* x  = (const float*)d_in[0];
    const float* Wk = (const float*)d_in[1];
    // d_in[2]=bk (cancels in token-softmax); d_in[3]=Wq, d_in[4]=bq (softmax over
    // size-1 head-channel axis -> identically 1.0, so Wq/bq are dead)
    const float* Wv = (const float*)d_in[5];
    const float* bv = (const float*)d_in[6];
    const float* Wr = (const float*)d_in[7];
    const float* br = (const float*)d_in[8];
    float* out = (float*)d_out;
    float* ws  = (float*)d_ws;

    hipMemsetAsync(ws, 0, (WS_RC) * sizeof(float), stream);  // zero S + m accumulators
    ea3d_reduce<<<dim3(GRIDX, NB), 256, 0, stream>>>(x, Wk, ws);
    ea3d_finalize<<<1, 256, 0, stream>>>(Wv, bv, Wr, br, ws);
    ea3d_add<<<dim3(32, NB * NCH), 256, 0, stream>>>(x, ws, out);
}